// Round 6
// baseline (138.551 us; speedup 1.0000x reference)
//
#include <hip/hip_runtime.h>

#define TT 20
#define NSTK 1000
#define THREADS 256
#define NBLK 2000

typedef float f32x4 __attribute__((ext_vector_type(4)));
typedef _Float16 f16x8 __attribute__((ext_vector_type(8)));

__device__ __forceinline__ float rcp_f(float x) { return __builtin_amdgcn_rcpf(x); }
__device__ __forceinline__ float sigmoid_f(float x) { return rcp_f(1.0f + __expf(-x)); }
__device__ __forceinline__ float tanh_f(float x) {
    return 1.0f - 2.0f * rcp_f(__expf(2.0f * x) + 1.0f);
}

// A/B fragment k-convention: k = kf*32 + q*8 + j  (q = lane>>4, j = elem).
// Same bijection for A and B, so the true HW k-permutation cancels.
// A-frag LDS layout: [kf][q][row][j] shorts. kf 0,1 = x rows; kf 2,3 = h rows.
// This block's 4 batches live in rows {0,1,4,5}; all other rows are dead
// (their C rows are discarded; row-independence of MFMA makes garbage safe).
#define AIDX(kf, q, row, j) ((((kf) * 4 + (q)) * 16 + (row)) * 8 + (j))

extern "C" __global__ void __launch_bounds__(THREADS, 4)
lstm_att_f16(const float* __restrict__ x,
             const float* __restrict__ Wi, const float* __restrict__ bi,
             const float* __restrict__ Wo, const float* __restrict__ bo,
             const float* __restrict__ Wf, const float* __restrict__ bf_,
             const float* __restrict__ Wc, const float* __restrict__ bc,
             const float* __restrict__ Wt,
             float* __restrict__ out)
{
    __shared__ __align__(16) _Float16 afrag[2][2048];     // 8 KB  xh frags, double-buffered
    __shared__ __align__(16) _Float16 hhist[TT * 4 * 64]; // 10 KB h history (4 batches)

    // XCD-coherent swizzle: a stock's two halves (idx, idx+8) land on the same XCD
    const int idx  = blockIdx.x;
    const int half = (idx >> 3) & 1;
    const int n    = ((idx >> 4) << 3) | (idx & 7);

    const int tid  = threadIdx.x;
    const int lane = tid & 63;
    const int w    = tid >> 6;            // wave 0..3
    const int q    = lane >> 4;           // k-subgroup
    const int r16  = lane & 15;           // A row / B col within frag
    const int dcol = w * 16 + r16;        // this lane's d column (0..63)
    const bool hi  = lane >= 32;
    const int g16  = lane >> 4;
    // after shfl: lanes 0-15 own C row 0, 16-31 row 4, 32-47 row 1, 48-63 row 5
    const int rowh = ((g16 >> 1) & 1) | ((g16 & 1) << 2);   // {0,4,1,5}
    const int bbh  = (rowh & 1) | (rowh >> 1);              // local batch {0,2,1,3}

    // ---- persistent weight B-frags, direct global->reg ----
    f16x8 bw[4][4];                       // [gate][kf]
    {
        const float* Wg[4] = {Wi, Wo, Wf, Wc};
        #pragma unroll
        for (int g = 0; g < 4; ++g) {
            const float* base = Wg[g] + (size_t)n * 8192 + dcol;
            #pragma unroll
            for (int kf = 0; kf < 4; ++kf)
                #pragma unroll
                for (int j = 0; j < 8; ++j)
                    bw[g][kf][j] = (_Float16)base[(kf * 32 + q * 8 + j) * 64];
        }
    }
    float biasv[4];
    biasv[0] = bi[n * 64 + dcol];
    biasv[1] = bo[n * 64 + dcol];
    biasv[2] = bf_[n * 64 + dcol];
    biasv[3] = bc[n * 64 + dcol];

    // ---- x staging role: thread -> (local batch sb, dim dxx) ----
    const int sb  = tid >> 6;                       // 0..3
    const int dxx = tid & 63;
    const int rr  = (sb & 1) | ((sb >> 1) << 2);    // batch -> row {0,1,4,5}
    const int sslot = AIDX(dxx >> 5, (dxx & 31) >> 3, rr, dxx & 7);
    const float* xptr = x + ((size_t)(half * 4 + sb) * TT * NSTK + (size_t)n) * 64 + dxx;

    // init: stage x(t=0) into buf0; zero h rows of buf0 (kf 2,3 region)
    afrag[0][sslot] = (_Float16)(*xptr);
    #pragma unroll
    for (int u = 0; u < 4; ++u)
        afrag[0][1024 + tid + u * THREADS] = (_Float16)0.0f;
    float xreg = *(xptr + (size_t)NSTK * 64);       // prefetch t=1

    float cst = 0.f;                                // cell state for (rowh, dcol)

    __syncthreads();

    const int kkh   = dcol & 31;
    const int hslot = AIDX(2 + (dcol >> 5), kkh >> 3, rowh, kkh & 7);

    for (int t = 0; t < TT; ++t) {
        const int cur = t & 1, nxt = cur ^ 1;

        // A-frag reads from current buffer
        f16x8 af[4];
        #pragma unroll
        for (int kf = 0; kf < 4; ++kf)
            af[kf] = *(const f16x8*)(&afrag[cur][AIDX(kf, q, r16, 0)]);

        // stage x(t+1) into next buffer; prefetch t+2 (hidden under MFMA)
        if (t + 1 < TT)
            afrag[nxt][sslot] = (_Float16)xreg;
        {
            const int tn = (t + 2 < TT) ? t + 2 : TT - 1;
            xreg = *(xptr + (size_t)tn * NSTK * 64);
        }

        f32x4 acc[4];
        #pragma unroll
        for (int g = 0; g < 4; ++g)
            acc[g] = (f32x4){biasv[g], biasv[g], biasv[g], biasv[g]};
        #pragma unroll
        for (int kf = 0; kf < 4; ++kf) {
            #pragma unroll
            for (int g = 0; g < 4; ++g)
                acc[g] = __builtin_amdgcn_mfma_f32_16x16x32_f16(af[kf], bw[g][kf], acc[g], 0, 0, 0);
        }

        // ship C row-reg 1 to partner lane (+32); every lane then owns exactly 1 row
        float pg[4];
        #pragma unroll
        for (int g = 0; g < 4; ++g) {
            const float t1 = __shfl_xor(acc[g][1], 32, 64);
            pg[g] = hi ? t1 : acc[g][0];
        }

        const float ig = sigmoid_f(pg[0]), og = sigmoid_f(pg[1]);
        const float fg = sigmoid_f(pg[2]), cg = tanh_f(pg[3]);
        cst = fmaf(fg, cst, ig * cg);
        const float hv = og * tanh_f(cst);

        // h -> next buffer's A-frag + history
        afrag[nxt][hslot] = (_Float16)hv;
        hhist[(t * 4 + bbh) * 64 + dcol] = (_Float16)hv;

        __syncthreads();   // publishes x(t+1)+h(t) in buf[nxt]; closes reads of buf[cur]
    }

    // ---- deferred attention: wave w handles local batch w ----
    const float* wtg = Wt + (size_t)n * (TT * 64);
    {
        float s[TT];
        #pragma unroll
        for (int t = 0; t < TT; ++t)
            s[t] = (float)hhist[(t * 4 + w) * 64 + lane] * wtg[t * 64 + lane];
        #pragma unroll
        for (int t = 0; t < TT; ++t) {
            #pragma unroll
            for (int mk = 32; mk >= 1; mk >>= 1)
                s[t] += __shfl_xor(s[t], mk, 64);
        }
        float m = s[0];
        #pragma unroll
        for (int t = 1; t < TT; ++t) m = fmaxf(m, s[t]);
        float se = 0.f;
        #pragma unroll
        for (int t = 0; t < TT; ++t) { s[t] = __expf(s[t] - m); se += s[t]; }
        const float rs = rcp_f(se);
        float o = 0.f;
        #pragma unroll
        for (int t = 0; t < TT; ++t)
            o = fmaf(s[t], (float)hhist[(t * 4 + w) * 64 + lane], o);
        out[((size_t)(half * 4 + w) * NSTK + n) * 64 + lane] = o * rs;
    }
}

extern "C" void kernel_launch(void* const* d_in, const int* in_sizes, int n_in,
                              void* d_out, int out_size, void* d_ws, size_t ws_size,
                              hipStream_t stream) {
    const float* x  = (const float*)d_in[0];
    const float* Wi = (const float*)d_in[1];
    const float* bi = (const float*)d_in[2];
    const float* Wo = (const float*)d_in[3];
    const float* bo = (const float*)d_in[4];
    const float* Wf = (const float*)d_in[5];
    const float* bf = (const float*)d_in[6];
    const float* Wc = (const float*)d_in[7];
    const float* bc = (const float*)d_in[8];
    const float* Wt = (const float*)d_in[9];
    float* out = (float*)d_out;

    lstm_att_f16<<<NBLK, THREADS, 0, stream>>>(
        x, Wi, bi, Wo, bo, Wf, bf, Wc, bc, Wt, out);
}

// Round 7
// 74.838 us; speedup vs baseline: 1.8513x; 1.8513x over previous
//
#include <hip/hip_runtime.h>

#define TT 20
#define NSTK 1000
#define THREADS 256

#define SC_SIG  1.44269504089f      // log2(e)
#define SC_TANH 2.88539008178f      // 2*log2(e)

typedef float f32x4 __attribute__((ext_vector_type(4)));
typedef _Float16 f16x8 __attribute__((ext_vector_type(8)));
typedef _Float16 f16x2 __attribute__((ext_vector_type(2)));

__device__ __forceinline__ float rcp_f(float x) { return __builtin_amdgcn_rcpf(x); }
__device__ __forceinline__ float exp2_f(float x) { return __builtin_amdgcn_exp2f(x); }

// A/B fragment k-convention: k = kf*32 + q*8 + j  (q = lane>>4, j = elem).
// Same bijection for A and B, so the true HW k-permutation cancels.
// A-frag LDS layout: [kf][q][row][j] shorts. kf 0,1 = x rows; kf 2,3 = h rows.
#define AIDX(kf, q, row, j) ((((kf) * 4 + (q)) * 16 + (row)) * 8 + (j))

extern "C" __global__ void __launch_bounds__(THREADS, 4)
lstm_att_f16(const float* __restrict__ x,
             const float* __restrict__ Wi, const float* __restrict__ bi,
             const float* __restrict__ Wo, const float* __restrict__ bo,
             const float* __restrict__ Wf, const float* __restrict__ bf_,
             const float* __restrict__ Wc, const float* __restrict__ bc,
             const float* __restrict__ Wt,
             float* __restrict__ out)
{
    // 32 KB LDS, time-shared:
    //   prologue: wstage[2][4096] f32 (2 x 16 KB chunk double-buffer)
    //   loop:     afrag[2][2048] f16 (8 KB) + hhist[20*8*64] f16 (20 KB)
    __shared__ __align__(16) char smem[32768];
    _Float16 (*afrag)[2048] = (_Float16 (*)[2048])smem;
    _Float16* hhist = (_Float16*)(smem + 8192);

    const int n    = blockIdx.x;
    const int tid  = threadIdx.x;
    const int lane = tid & 63;
    const int w    = tid >> 6;            // wave 0..3
    const int q    = lane >> 4;           // k-subgroup
    const int r16  = lane & 15;           // A row / B col within frag
    const int dcol = w * 16 + r16;        // this lane's d column (0..63)
    const bool hi  = lane >= 32;
    const int rowbase = ((lane & 31) >> 4) * 4 + (hi ? 2 : 0);  // this lane's 2 batch rows

    // ---- coalesced weight prologue: 8 chunks of 16 KB (64 k-rows), dbuf ----
    f16x8 bw[4][4];                       // [gate][kf], log2e-prescaled f16
    {
        const float* Wg[4] = {Wi, Wo, Wf, Wc};
        float4* wst[2] = { (float4*)smem, (float4*)(smem + 16384) };
        float4 reg[4];
        {
            const float4* src = (const float4*)(Wg[0] + (size_t)n * 8192);
            #pragma unroll
            for (int u = 0; u < 4; ++u) reg[u] = src[u * 256 + tid];
        }
        #pragma unroll
        for (int c = 0; c < 8; ++c) {
            const int g = c >> 1, hf = c & 1, buf = c & 1;
            float4* wb = wst[buf];
            #pragma unroll
            for (int u = 0; u < 4; ++u) wb[u * 256 + tid] = reg[u];
            if (c + 1 < 8) {    // prefetch next chunk (latency hides under barrier+reads)
                const int g2 = (c + 1) >> 1, hf2 = (c + 1) & 1;
                const float4* src = (const float4*)(Wg[g2] + (size_t)n * 8192 + hf2 * 4096);
                #pragma unroll
                for (int u = 0; u < 4; ++u) reg[u] = src[u * 256 + tid];
            }
            __syncthreads();              // chunk c staged
            const float* wf = (const float*)wst[buf];
            const float sc = (g == 3) ? SC_TANH : SC_SIG;
            #pragma unroll
            for (int kfl = 0; kfl < 2; ++kfl)
                #pragma unroll
                for (int j = 0; j < 8; ++j)
                    bw[g][hf * 2 + kfl][j] =
                        (_Float16)(wf[(kfl * 32 + q * 8 + j) * 64 + dcol] * sc);
            __syncthreads();              // all reads of buf done; reusable at c+2
        }
    }
    float biasv[4];
    biasv[0] = bi[n * 64 + dcol]  * SC_SIG;
    biasv[1] = bo[n * 64 + dcol]  * SC_SIG;
    biasv[2] = bf_[n * 64 + dcol] * SC_SIG;
    biasv[3] = bc[n * 64 + dcol]  * SC_TANH;

    // ---- x staging role: thread -> (batch sb, dims dx,dx+1) ----
    const int sb = tid >> 5, dx = (tid & 31) * 2;
    const int sbase = AIDX(dx >> 5, (dx & 31) >> 3, sb, dx & 7);
    const float* xptr = x + ((size_t)sb * TT * NSTK + (size_t)n) * 64 + dx;

    // init: stage x(t=0) into buf0; zero h rows of buf0 (safe: prologue fully done)
    {
        const float2 x0 = *(const float2*)xptr;
        *(f16x2*)(&afrag[0][sbase]) = (f16x2){(_Float16)x0.x, (_Float16)x0.y};
        #pragma unroll
        for (int u = 0; u < 4; ++u)
            afrag[0][1024 + tid + u * THREADS] = (_Float16)0.0f;
    }
    float2 xreg = *(const float2*)(xptr + (size_t)NSTK * 64);   // prefetch t=1

    float cst0 = 0.f, cst1 = 0.f;        // cell state for rows rowbase, rowbase+1

    __syncthreads();

    const int kfh = 2 + (dcol >> 5), kkh = dcol & 31;
    const int hb0 = AIDX(kfh, kkh >> 3, rowbase, kkh & 7);      // h slot, row rowbase

    for (int t = 0; t < TT; ++t) {
        const int cur = t & 1, nxt = cur ^ 1;

        // A-frag reads from current buffer
        f16x8 af[4];
        #pragma unroll
        for (int kf = 0; kf < 4; ++kf)
            af[kf] = *(const f16x8*)(&afrag[cur][AIDX(kf, q, r16, 0)]);

        // stage x(t+1) into next buffer; prefetch t+2 (hidden under MFMA)
        if (t + 1 < TT)
            *(f16x2*)(&afrag[nxt][sbase]) = (f16x2){(_Float16)xreg.x, (_Float16)xreg.y};
        {
            const int tn = (t + 2 < TT) ? t + 2 : TT - 1;
            xreg = *(const float2*)(xptr + (size_t)tn * NSTK * 64);
        }

        f32x4 acc[4];
        #pragma unroll
        for (int g = 0; g < 4; ++g)
            acc[g] = (f32x4){biasv[g], biasv[g], biasv[g], biasv[g]};
        #pragma unroll
        for (int kf = 0; kf < 4; ++kf) {
            #pragma unroll
            for (int g = 0; g < 4; ++g)
                acc[g] = __builtin_amdgcn_mfma_f32_16x16x32_f16(af[kf], bw[g][kf], acc[g], 0, 0, 0);
        }

        // ship C rows 2,3 to partner lane (+32); every lane then handles 2 rows
        float p0[4], p1[4];
        #pragma unroll
        for (int g = 0; g < 4; ++g) {
            const float t2 = __shfl_xor(acc[g][2], 32, 64);
            const float t3 = __shfl_xor(acc[g][3], 32, 64);
            p0[g] = hi ? t2 : acc[g][0];
            p1[g] = hi ? t3 : acc[g][1];
        }

        // gates via raw v_exp_f32 (log2e folded into weights/bias)
        const float ig0 = rcp_f(1.0f + exp2_f(-p0[0]));
        const float og0 = rcp_f(1.0f + exp2_f(-p0[1]));
        const float fg0 = rcp_f(1.0f + exp2_f(-p0[2]));
        const float cg0 = 1.0f - 2.0f * rcp_f(exp2_f(p0[3]) + 1.0f);
        const float ig1 = rcp_f(1.0f + exp2_f(-p1[0]));
        const float og1 = rcp_f(1.0f + exp2_f(-p1[1]));
        const float fg1 = rcp_f(1.0f + exp2_f(-p1[2]));
        const float cg1 = 1.0f - 2.0f * rcp_f(exp2_f(p1[3]) + 1.0f);
        cst0 = fmaf(fg0, cst0, ig0 * cg0);
        cst1 = fmaf(fg1, cst1, ig1 * cg1);
        const float th0 = 1.0f - 2.0f * rcp_f(exp2_f(cst0 * SC_TANH) + 1.0f);
        const float th1 = 1.0f - 2.0f * rcp_f(exp2_f(cst1 * SC_TANH) + 1.0f);
        const float h0 = og0 * th0;
        const float h1 = og1 * th1;

        // h -> next buffer's A-frag + history
        afrag[nxt][hb0]     = (_Float16)h0;
        afrag[nxt][hb0 + 8] = (_Float16)h1;
        hhist[(t * 8 + rowbase) * 64 + dcol]     = (_Float16)h0;
        hhist[(t * 8 + rowbase + 1) * 64 + dcol] = (_Float16)h1;

        __syncthreads();   // publishes x(t+1)+h(t) in buf[nxt]; closes reads of buf[cur]
    }

    // ---- deferred attention: wave w handles batches 2w, 2w+1 ----
    const float* wtg = Wt + (size_t)n * (TT * 64);
    #pragma unroll
    for (int bb = 0; bb < 2; ++bb) {
        const int b = 2 * w + bb;
        float s[TT];
        #pragma unroll
        for (int t = 0; t < TT; ++t)
            s[t] = (float)hhist[(t * 8 + b) * 64 + lane] * wtg[t * 64 + lane];
        #pragma unroll
        for (int t = 0; t < TT; ++t) {
            #pragma unroll
            for (int mk = 32; mk >= 1; mk >>= 1)
                s[t] += __shfl_xor(s[t], mk, 64);
        }
        float m = s[0];
        #pragma unroll
        for (int t = 1; t < TT; ++t) m = fmaxf(m, s[t]);
        float se = 0.f;
        #pragma unroll
        for (int t = 0; t < TT; ++t) { s[t] = exp2_f((s[t] - m) * SC_SIG); se += s[t]; }
        const float rs = rcp_f(se);
        float o = 0.f;
        #pragma unroll
        for (int t = 0; t < TT; ++t)
            o = fmaf(s[t], (float)hhist[(t * 8 + b) * 64 + lane], o);
        out[((size_t)b * NSTK + n) * 64 + lane] = o * rs;
    }
}

extern "C" void kernel_launch(void* const* d_in, const int* in_sizes, int n_in,
                              void* d_out, int out_size, void* d_ws, size_t ws_size,
                              hipStream_t stream) {
    const float* x  = (const float*)d_in[0];
    const float* Wi = (const float*)d_in[1];
    const float* bi = (const float*)d_in[2];
    const float* Wo = (const float*)d_in[3];
    const float* bo = (const float*)d_in[4];
    const float* Wf = (const float*)d_in[5];
    const float* bf = (const float*)d_in[6];
    const float* Wc = (const float*)d_in[7];
    const float* bc = (const float*)d_in[8];
    const float* Wt = (const float*)d_in[9];
    float* out = (float*)d_out;

    lstm_att_f16<<<NSTK, THREADS, 0, stream>>>(
        x, Wi, bi, Wo, bo, Wf, bf, Wc, bc, Wt, out);
}